// Round 4
// baseline (237.869 us; speedup 1.0000x reference)
//
#include <hip/hip_runtime.h>
#include <math.h>

typedef __attribute__((ext_vector_type(8))) short bf16x8;
typedef __attribute__((ext_vector_type(4))) float f32x4;

__device__ __forceinline__ short f2b(float f) {
  union { float f; unsigned u; } v; v.f = f;
  unsigned u = v.u + 0x7fffu + ((v.u >> 16) & 1u);
  return (short)(u >> 16);
}

// ---------------------------------------------------------------------------
// MFMA K-loop helper: A rows row0..row0+15 from global fp32 X (stride K),
// converted on the fly; wave w covers 64 cols of bf16 W[N][K].
// A/B frag: [idx=lane&15][k=(lane>>4)*8+j]; D: col=lane&15,row=(lane>>4)*4+reg
// ---------------------------------------------------------------------------
template <int K>
__device__ __forceinline__ void mfma_rows16(
    const float* __restrict__ X, const unsigned short* __restrict__ Wb,
    int row0, int lane, int w, f32x4 acc[4]) {
  int m = lane & 15, q = lane >> 4;
  const float* ap = X + (size_t)(row0 + m) * K + q * 8;
#pragma unroll
  for (int ks = 0; ks < K; ks += 32, ap += 32) {
    float4 a01 = *(const float4*)ap;
    float4 a23 = *(const float4*)(ap + 4);
    bf16x8 af;
    af[0] = f2b(a01.x); af[1] = f2b(a01.y); af[2] = f2b(a01.z); af[3] = f2b(a01.w);
    af[4] = f2b(a23.x); af[5] = f2b(a23.y); af[6] = f2b(a23.z); af[7] = f2b(a23.w);
#pragma unroll
    for (int nt = 0; nt < 4; ++nt) {
      int n = w * 64 + nt * 16 + m;
      bf16x8 bf = *(const bf16x8*)(Wb + (size_t)n * K + ks + q * 8);
      acc[nt] = __builtin_amdgcn_mfma_f32_16x16x32_bf16(af, bf, acc[nt], 0, 0, 0);
    }
  }
}

// ---------------------------------------------------------------------------
// K0: convert weights to bf16 (con_w1 repacked to Wab[512][256])
// ---------------------------------------------------------------------------
__global__ __launch_bounds__(256) void k_cvt(
    const float* __restrict__ w1, const float* __restrict__ w2,
    const float* __restrict__ wq, const float* __restrict__ wc,
    unsigned short* __restrict__ o) {
  int base = (blockIdx.x * 256 + threadIdx.x) * 4;
#pragma unroll
  for (int u = 0; u < 4; ++u) {
    int idx = base + u;
    float v;
    if (idx < 131072) v = w1[idx];
    else if (idx < 196608) v = w2[idx - 131072];
    else if (idx < 393216) v = wq[idx - 196608];
    else {
      int i = idx - 393216, n = i >> 8, k = i & 255;
      v = (n < 256) ? wc[n * 512 + k] : wc[(n - 256) * 512 + 256 + k];
    }
    o[idx] = (unsigned short)f2b(v);
  }
}

// ---------------------------------------------------------------------------
// MEGA1: enc1+LN+relu -> enc2 -> qkv & a/b, one block per 16 rows.
// r and mf live only in LDS (bf16, row stride 264 to balance banks).
// ---------------------------------------------------------------------------
__global__ __launch_bounds__(256) void k_mega1(
    const float* __restrict__ me,
    const unsigned short* __restrict__ wb1, const float* __restrict__ b1,
    const float* __restrict__ g, const float* __restrict__ lb,
    const unsigned short* __restrict__ wb2, const float* __restrict__ b2,
    const unsigned short* __restrict__ wqk, const float* __restrict__ bq,
    const unsigned short* __restrict__ wab, const float* __restrict__ cb1,
    float* __restrict__ qkv, float* __restrict__ amat,
    float* __restrict__ bmat) {
  __shared__ float hh[16 * 260];
  __shared__ unsigned short rA[16 * 264];
  __shared__ unsigned short mfA[16 * 264];
  int tid = threadIdx.x, lane = tid & 63, w = tid >> 6;
  int row0 = blockIdx.x * 16;
  int m = lane & 15, q = lane >> 4;

  // ---- stage A: enc1 (K=512)
  {
    f32x4 acc[4];
#pragma unroll
    for (int i = 0; i < 4; ++i) acc[i] = (f32x4){0.f, 0.f, 0.f, 0.f};
    mfma_rows16<512>(me, wb1, row0, lane, w, acc);
#pragma unroll
    for (int nt = 0; nt < 4; ++nt) {
      int col = w * 64 + nt * 16 + m;
      float bias = b1[col];
#pragma unroll
      for (int reg = 0; reg < 4; ++reg)
        hh[(q * 4 + reg) * 260 + col] = acc[nt][reg] + bias;
    }
  }
  __syncthreads();
  // ---- LN + relu -> rA (bf16)
  {
    float4 g4 = *(const float4*)(g + lane * 4);
    float4 lb4 = *(const float4*)(lb + lane * 4);
#pragma unroll
    for (int rr = 0; rr < 4; ++rr) {
      int r = w * 4 + rr;
      float4 v = *(const float4*)&hh[r * 260 + lane * 4];
      float s1 = v.x + v.y + v.z + v.w;
      float s2 = v.x * v.x + v.y * v.y + v.z * v.z + v.w * v.w;
#pragma unroll
      for (int o = 32; o > 0; o >>= 1) {
        s1 += __shfl_xor(s1, o, 64);
        s2 += __shfl_xor(s2, o, 64);
      }
      float mu = s1 * (1.f / 256.f);
      float var = s2 * (1.f / 256.f) - mu * mu;
      float rs = rsqrtf(var + 1e-5f);
      unsigned short y0 = (unsigned short)f2b(fmaxf((v.x - mu) * rs * g4.x + lb4.x, 0.f));
      unsigned short y1 = (unsigned short)f2b(fmaxf((v.y - mu) * rs * g4.y + lb4.y, 0.f));
      unsigned short y2 = (unsigned short)f2b(fmaxf((v.z - mu) * rs * g4.z + lb4.z, 0.f));
      unsigned short y3 = (unsigned short)f2b(fmaxf((v.w - mu) * rs * g4.w + lb4.w, 0.f));
      uint2 pk;
      pk.x = (unsigned)y0 | ((unsigned)y1 << 16);
      pk.y = (unsigned)y2 | ((unsigned)y3 << 16);
      *(uint2*)&rA[r * 264 + lane * 4] = pk;
    }
  }
  __syncthreads();
  // ---- stage B: enc2 (K=256) from rA -> mfA (bf16)
  {
    f32x4 acc[4];
#pragma unroll
    for (int i = 0; i < 4; ++i) acc[i] = (f32x4){0.f, 0.f, 0.f, 0.f};
#pragma unroll
    for (int ks = 0; ks < 256; ks += 32) {
      bf16x8 af = *(const bf16x8*)&rA[m * 264 + ks + q * 8];
#pragma unroll
      for (int nt = 0; nt < 4; ++nt) {
        int n = w * 64 + nt * 16 + m;
        bf16x8 bf = *(const bf16x8*)(wb2 + (size_t)n * 256 + ks + q * 8);
        acc[nt] = __builtin_amdgcn_mfma_f32_16x16x32_bf16(af, bf, acc[nt], 0, 0, 0);
      }
    }
#pragma unroll
    for (int nt = 0; nt < 4; ++nt) {
      int col = w * 64 + nt * 16 + m;
      float bias = b2[col];
#pragma unroll
      for (int reg = 0; reg < 4; ++reg)
        mfA[(q * 4 + reg) * 264 + col] = (unsigned short)f2b(acc[nt][reg] + bias);
    }
  }
  __syncthreads();
  // ---- stage C: qkv (N=768) from mfA
  {
    f32x4 acc[12];
#pragma unroll
    for (int i = 0; i < 12; ++i) acc[i] = (f32x4){0.f, 0.f, 0.f, 0.f};
#pragma unroll
    for (int ks = 0; ks < 256; ks += 32) {
      bf16x8 af = *(const bf16x8*)&mfA[m * 264 + ks + q * 8];
#pragma unroll
      for (int p = 0; p < 3; ++p)
#pragma unroll
        for (int nt = 0; nt < 4; ++nt) {
          int n = p * 256 + w * 64 + nt * 16 + m;
          bf16x8 bf = *(const bf16x8*)(wqk + (size_t)n * 256 + ks + q * 8);
          acc[p * 4 + nt] = __builtin_amdgcn_mfma_f32_16x16x32_bf16(af, bf, acc[p * 4 + nt], 0, 0, 0);
        }
    }
#pragma unroll
    for (int p = 0; p < 3; ++p)
#pragma unroll
      for (int nt = 0; nt < 4; ++nt) {
        int col = p * 256 + w * 64 + nt * 16 + m;
        float bias = bq[col];
#pragma unroll
        for (int reg = 0; reg < 4; ++reg)
          qkv[(size_t)(row0 + q * 4 + reg) * 768 + col] = acc[p * 4 + nt][reg] + bias;
      }
  }
  // ---- stage D: a/b (N=512) from mfA
  {
    f32x4 acc[8];
#pragma unroll
    for (int i = 0; i < 8; ++i) acc[i] = (f32x4){0.f, 0.f, 0.f, 0.f};
#pragma unroll
    for (int ks = 0; ks < 256; ks += 32) {
      bf16x8 af = *(const bf16x8*)&mfA[m * 264 + ks + q * 8];
#pragma unroll
      for (int p = 0; p < 2; ++p)
#pragma unroll
        for (int nt = 0; nt < 4; ++nt) {
          int n = p * 256 + w * 64 + nt * 16 + m;
          bf16x8 bf = *(const bf16x8*)(wab + (size_t)n * 256 + ks + q * 8);
          acc[p * 4 + nt] = __builtin_amdgcn_mfma_f32_16x16x32_bf16(af, bf, acc[p * 4 + nt], 0, 0, 0);
        }
    }
#pragma unroll
    for (int nt = 0; nt < 4; ++nt) {
      int col = w * 64 + nt * 16 + m;
      float ba = cb1[col];
#pragma unroll
      for (int reg = 0; reg < 4; ++reg) {
        int row = row0 + q * 4 + reg;
        amat[(size_t)row * 256 + col] = acc[nt][reg] + ba;
        bmat[(size_t)row * 256 + col] = acc[4 + nt][reg];
      }
    }
  }
}

// ---------------------------------------------------------------------------
// ATTN fused: QK^T (fp32 VALU) + softmax + PV (bf16 MFMA).
// grid = (b,h,sg) = 512 blocks; writes attn (fp32) and ctx.
// ---------------------------------------------------------------------------
__global__ __launch_bounds__(256) void k_attn_fused(
    const float* __restrict__ qkv, float* __restrict__ attn,
    float* __restrict__ ctx) {
  __shared__ float qs[32 * 32];
  __shared__ unsigned short ps[32 * 264];
  __shared__ unsigned short vt[32 * 264];
  int blk = blockIdx.x;
  int sg = blk & 7, bh = blk >> 3, h = bh & 7, b = bh >> 3;
  int tid = threadIdx.x, lane = tid & 63, w = tid >> 6;
  // stage Q tile (fp32)
  {
    int r = tid >> 3, c4 = tid & 7;
    float4 v = *(const float4*)(qkv + ((size_t)(b * 256 + sg * 32 + r)) * 768 + h * 32 + c4 * 4);
    *(float4*)&qs[r * 32 + c4 * 4] = v;
  }
  // stage V^T (bf16): vt[d][t], thread tid = t
  {
    const float4* vr = (const float4*)(qkv + ((size_t)(b * 256 + tid)) * 768 + 512 + h * 32);
#pragma unroll
    for (int d4 = 0; d4 < 8; ++d4) {
      float4 vv = vr[d4];
      vt[(d4 * 4 + 0) * 264 + tid] = (unsigned short)f2b(vv.x);
      vt[(d4 * 4 + 1) * 264 + tid] = (unsigned short)f2b(vv.y);
      vt[(d4 * 4 + 2) * 264 + tid] = (unsigned short)f2b(vv.z);
      vt[(d4 * 4 + 3) * 264 + tid] = (unsigned short)f2b(vv.w);
    }
  }
  __syncthreads();
  // scores: wave w owns rows r0..r0+7; lane covers t = tt*64+lane
  int r0 = w * 8;
  float sc[8][4];
#pragma unroll
  for (int r = 0; r < 8; ++r)
#pragma unroll
    for (int tt = 0; tt < 4; ++tt) sc[r][tt] = 0.f;
#pragma unroll
  for (int tt = 0; tt < 4; ++tt) {
    int t = tt * 64 + lane;
    const float4* kp = (const float4*)(qkv + ((size_t)(b * 256 + t)) * 768 + 256 + h * 32);
#pragma unroll
    for (int d4 = 0; d4 < 8; ++d4) {
      float4 kv = kp[d4];
#pragma unroll
      for (int r = 0; r < 8; ++r) {
        float4 qv = *(const float4*)&qs[(r0 + r) * 32 + d4 * 4];
        sc[r][tt] += qv.x * kv.x + qv.y * kv.y + qv.z * kv.z + qv.w * kv.w;
      }
    }
  }
  const float scale = 0.17677669529663689f;
  float* arow_base = attn + ((size_t)(bh * 256 + sg * 32 + r0)) * 256;
  for (int r = 0; r < 8; ++r) {
    float v0 = sc[r][0] * scale, v1 = sc[r][1] * scale;
    float v2 = sc[r][2] * scale, v3 = sc[r][3] * scale;
    float mx = fmaxf(fmaxf(v0, v1), fmaxf(v2, v3));
#pragma unroll
    for (int o = 32; o > 0; o >>= 1) mx = fmaxf(mx, __shfl_xor(mx, o, 64));
    float e0 = expf(v0 - mx), e1 = expf(v1 - mx), e2 = expf(v2 - mx), e3 = expf(v3 - mx);
    float s = e0 + e1 + e2 + e3;
#pragma unroll
    for (int o = 32; o > 0; o >>= 1) s += __shfl_xor(s, o, 64);
    float inv = 1.f / s;
    float p0 = e0 * inv, p1 = e1 * inv, p2 = e2 * inv, p3 = e3 * inv;
    float* arow = arow_base + r * 256;
    arow[lane] = p0; arow[64 + lane] = p1;
    arow[128 + lane] = p2; arow[192 + lane] = p3;
    unsigned short* prow = ps + (r0 + r) * 264;
    prow[lane] = (unsigned short)f2b(p0);
    prow[64 + lane] = (unsigned short)f2b(p1);
    prow[128 + lane] = (unsigned short)f2b(p2);
    prow[192 + lane] = (unsigned short)f2b(p3);
  }
  __syncthreads();
  // PV via MFMA: wave w -> tile (mt = w&1 rows, dt = w>>1 cols)
  {
    int mt = w & 1, dt = w >> 1;
    int mm = lane & 15, qq = lane >> 4;
    f32x4 a = (f32x4){0.f, 0.f, 0.f, 0.f};
#pragma unroll
    for (int ks = 0; ks < 256; ks += 32) {
      bf16x8 af = *(const bf16x8*)&ps[(mt * 16 + mm) * 264 + ks + qq * 8];
      bf16x8 bf = *(const bf16x8*)&vt[(dt * 16 + mm) * 264 + ks + qq * 8];
      a = __builtin_amdgcn_mfma_f32_16x16x32_bf16(af, bf, a, 0, 0, 0);
    }
#pragma unroll
    for (int reg = 0; reg < 4; ++reg) {
      int srow = sg * 32 + mt * 16 + qq * 4 + reg;
      ctx[((size_t)(b * 256 + srow)) * 256 + h * 32 + dt * 16 + mm] = a[reg];
    }
  }
}

// ---------------------------------------------------------------------------
// attn_weights = mean over heads (float4)
// ---------------------------------------------------------------------------
__global__ __launch_bounds__(256) void k_attn_mean(
    const float* __restrict__ attn, float* __restrict__ out_aw) {
  int idx = blockIdx.x * 256 + threadIdx.x;
  int b = idx >> 14;
  int st4 = idx & 16383;
  const float4* base = (const float4*)(attn + ((size_t)b << 19));
  float sx = 0, sy = 0, sz = 0, sw = 0;
#pragma unroll
  for (int h = 0; h < 8; ++h) {
    float4 v = base[h * 16384 + st4];
    sx += v.x; sy += v.y; sz += v.z; sw += v.w;
  }
  float4 r; r.x = sx * 0.125f; r.y = sy * 0.125f; r.z = sz * 0.125f; r.w = sw * 0.125f;
  ((float4*)out_aw)[idx] = r;
}

// ---------------------------------------------------------------------------
// pooled(ctx mean) -> out-proj -> cons/hall heads, one block per b
// ---------------------------------------------------------------------------
__global__ __launch_bounds__(256) void k_pool_heads(
    const float* __restrict__ ctx,
    const float* __restrict__ outw, const float* __restrict__ outb,
    const float* __restrict__ cw1, const float* __restrict__ cb1,
    const float* __restrict__ cw2, const float* __restrict__ cb2,
    const float* __restrict__ hw1, const float* __restrict__ hb1,
    const float* __restrict__ hw2, const float* __restrict__ hb2,
    float* __restrict__ out) {
  int b = blockIdx.x, j = threadIdx.x;
  __shared__ float pc[256];
  __shared__ float psh[256];
  __shared__ float red[4];
  float sm = 0.f;
  for (int t = 0; t < 256; ++t) sm += ctx[((size_t)(b * 256 + t)) * 256 + j];
  pc[j] = sm * (1.f / 256.f);
  __syncthreads();
  float s = outb[j];
  const float4* wr = (const float4*)(outw + (size_t)j * 256);
  for (int k4 = 0; k4 < 64; ++k4) {
    float4 wv = wr[k4];
    const float* p = pc + k4 * 4;
    s += p[0] * wv.x + p[1] * wv.y + p[2] * wv.z + p[3] * wv.w;
  }
  psh[j] = s;
  __syncthreads();
  int jj = j & 127;
  bool isH = j >= 128;
  const float* w1 = isH ? hw1 : cw1;
  const float* bb1 = isH ? hb1 : cb1;
  const float* w2 = isH ? hw2 : cw2;
  float a = bb1[jj];
  const float4* w1r = (const float4*)(w1 + (size_t)jj * 256);
  for (int k4 = 0; k4 < 64; ++k4) {
    float4 wv = w1r[k4];
    const float* p = psh + k4 * 4;
    a += p[0] * wv.x + p[1] * wv.y + p[2] * wv.z + p[3] * wv.w;
  }
  float v = fmaxf(a, 0.f) * w2[jj];
#pragma unroll
  for (int o = 32; o > 0; o >>= 1) v += __shfl_xor(v, o, 64);
  if ((j & 63) == 0) red[j >> 6] = v;
  __syncthreads();
  if (j == 0) {
    float c = red[0] + red[1] + cb2[0];
    float h = red[2] + red[3] + hb2[0];
    out[b] = 1.f / (1.f + expf(-c));
    out[8 + b] = 1.f / (1.f + expf(-h));
  }
}

// ---------------------------------------------------------------------------
// pair scores, LDS-tiled 32x32 upper-triangular tiles (amat includes con_b1)
// ---------------------------------------------------------------------------
__global__ __launch_bounds__(256) void k_pairs(
    const float* __restrict__ amat, const float* __restrict__ bmat,
    const float* __restrict__ cw2, const float* __restrict__ cb2,
    float* __restrict__ M) {
  __shared__ float As[32 * 130];
  __shared__ float Bs[32 * 130];
  __shared__ float w2s[256];
  int blk = blockIdx.x;
  int b = blk / 36, tix = blk % 36;
  int it = 0, rem = tix;
  while (rem >= 8 - it) { rem -= 8 - it; ++it; }
  int jt = it + rem;
  int tid = threadIdx.x;
  int tj = tid & 15, ti = tid >> 4;
  w2s[tid] = cw2[tid];
  float acc00 = 0, acc01 = 0, acc10 = 0, acc11 = 0;
  const float* Ab = amat + ((size_t)(b * 256 + it * 32)) * 256;
  const float* Bb = bmat + ((size_t)(b * 256 + jt * 32)) * 256;
  for (int ch = 0; ch < 2; ++ch) {
    __syncthreads();
#pragma unroll
    for (int k = 0; k < 4; ++k) {
      int f = tid + k * 256;
      int r = f >> 5, c4 = f & 31;
      float4 va = *(const float4*)(Ab + (size_t)r * 256 + ch * 128 + c4 * 4);
      float4 vb = *(const float4*)(Bb + (size_t)r * 256 + ch * 128 + c4 * 4);
      int la = r * 130 + c4 * 4;
      *(float2*)&As[la] = make_float2(va.x, va.y);
      *(float2*)&As[la + 2] = make_float2(va.z, va.w);
      *(float2*)&Bs[la] = make_float2(vb.x, vb.y);
      *(float2*)&Bs[la + 2] = make_float2(vb.z, vb.w);
    }
    __syncthreads();
    const float* a0 = As + (2 * ti) * 130;
    const float* a1 = a0 + 130;
    const float* b0 = Bs + (2 * tj) * 130;
    const float* b1 = b0 + 130;
    const float* w2c = w2s + ch * 128;
    for (int d = 0; d < 128; d += 4) {
#pragma unroll
      for (int k = 0; k < 4; ++k) {
        float w = w2c[d + k];
        float av0 = a0[d + k], av1 = a1[d + k];
        float bv0 = b0[d + k], bv1 = b1[d + k];
        acc00 += fmaxf(av0 + bv0, 0.f) * w;
        acc01 += fmaxf(av0 + bv1, 0.f) * w;
        acc10 += fmaxf(av1 + bv0, 0.f) * w;
        acc11 += fmaxf(av1 + bv1, 0.f) * w;
      }
    }
  }
  float c2 = cb2[0];
  float s00 = 1.f / (1.f + expf(-(acc00 + c2)));
  float s01 = 1.f / (1.f + expf(-(acc01 + c2)));
  float s10 = 1.f / (1.f + expf(-(acc10 + c2)));
  float s11 = 1.f / (1.f + expf(-(acc11 + c2)));
  float* Mb = M + ((size_t)b << 16);
  int i0 = it * 32 + 2 * ti, i1 = i0 + 1;
  int j0 = jt * 32 + 2 * tj, j1 = j0 + 1;
  if (it != jt) {
    Mb[i0 * 256 + j0] = s00; Mb[j0 * 256 + i0] = s00;
    Mb[i0 * 256 + j1] = s01; Mb[j1 * 256 + i0] = s01;
    Mb[i1 * 256 + j0] = s10; Mb[j0 * 256 + i1] = s10;
    Mb[i1 * 256 + j1] = s11; Mb[j1 * 256 + i1] = s11;
  } else {
    if (j0 > i0) { Mb[i0 * 256 + j0] = s00; Mb[j0 * 256 + i0] = s00; }
    else if (j0 == i0) Mb[i0 * 256 + j0] = 0.f;
    if (j1 > i0) { Mb[i0 * 256 + j1] = s01; Mb[j1 * 256 + i0] = s01; }
    if (j0 > i1) { Mb[i1 * 256 + j0] = s10; Mb[j0 * 256 + i1] = s10; }
    if (j1 > i1) { Mb[i1 * 256 + j1] = s11; Mb[j1 * 256 + i1] = s11; }
    else if (j1 == i1) Mb[i1 * 256 + j1] = 0.f;
  }
}

// ---------------------------------------------------------------------------
extern "C" void kernel_launch(void* const* d_in, const int* in_sizes, int n_in,
                              void* d_out, int out_size, void* d_ws, size_t ws_size,
                              hipStream_t stream) {
  const float* me        = (const float*)d_in[0];
  const float* enc_w1    = (const float*)d_in[1];
  const float* enc_b1    = (const float*)d_in[2];
  const float* ln_g      = (const float*)d_in[3];
  const float* ln_b      = (const float*)d_in[4];
  const float* enc_w2    = (const float*)d_in[5];
  const float* enc_b2    = (const float*)d_in[6];
  const float* in_proj_w = (const float*)d_in[7];
  const float* in_proj_b = (const float*)d_in[8];
  const float* out_w     = (const float*)d_in[9];
  const float* out_b     = (const float*)d_in[10];
  const float* cons_w1   = (const float*)d_in[11];
  const float* cons_b1   = (const float*)d_in[12];
  const float* cons_w2   = (const float*)d_in[13];
  const float* cons_b2   = (const float*)d_in[14];
  const float* hall_w1   = (const float*)d_in[15];
  const float* hall_b1   = (const float*)d_in[16];
  const float* hall_w2   = (const float*)d_in[17];
  const float* hall_b2   = (const float*)d_in[18];
  const float* con_w1    = (const float*)d_in[19];
  const float* con_b1    = (const float*)d_in[20];
  const float* con_w2    = (const float*)d_in[21];
  const float* con_b2    = (const float*)d_in[22];

  // workspace layout (float offsets)
  float* ws = (float*)d_ws;
  float* qkv  = ws;                    // 1572864
  float* attn = ws + 1572864;          // 4194304
  float* ctx  = ws + 5767168;          // 524288
  float* amat = ws + 6291456;          // 524288
  float* bmat = ws + 6815744;          // 524288
  unsigned short* wbf = (unsigned short*)(ws + 7340032);  // 524288 bf16

  unsigned short* wb1 = wbf;            // enc_w1  [256][512]
  unsigned short* wb2 = wbf + 131072;   // enc_w2  [256][256]
  unsigned short* wqk = wbf + 196608;   // in_proj [768][256]
  unsigned short* wab = wbf + 393216;   // con_w1 repacked [512][256]

  float* out    = (float*)d_out;
  float* out_M  = out + 16;
  float* out_aw = out + 16 + 524288;

  k_cvt<<<512, 256, 0, stream>>>(enc_w1, enc_w2, in_proj_w, con_w1, wbf);
  k_mega1<<<128, 256, 0, stream>>>(me, wb1, enc_b1, ln_g, ln_b,
                                   wb2, enc_b2, wqk, in_proj_b, wab, con_b1,
                                   qkv, amat, bmat);
  k_attn_fused<<<512, 256, 0, stream>>>(qkv, attn, ctx);
  k_attn_mean<<<512, 256, 0, stream>>>(attn, out_aw);
  k_pool_heads<<<8, 256, 0, stream>>>(ctx, out_w, out_b,
                                      cons_w1, cons_b1, cons_w2, cons_b2,
                                      hall_w1, hall_b1, hall_w2, hall_b2, out);
  k_pairs<<<288, 256, 0, stream>>>(amat, bmat, con_w2, con_b2, out_M);
}

// Round 7
// 201.793 us; speedup vs baseline: 1.1788x; 1.1788x over previous
//
#include <hip/hip_runtime.h>
#include <math.h>

typedef __attribute__((ext_vector_type(8))) short bf16x8;
typedef __attribute__((ext_vector_type(4))) float f32x4;

__device__ __forceinline__ short f2b(float f) {
  union { float f; unsigned u; } v; v.f = f;
  unsigned u = v.u + 0x7fffu + ((v.u >> 16) & 1u);
  return (short)(u >> 16);
}

// ---------------------------------------------------------------------------
// K0: convert weights to bf16 (con_w1 repacked to Wab[512][256]); block 0
// also zeroes poolctx (2048 floats) for the attention pooling atomics.
// ---------------------------------------------------------------------------
__global__ __launch_bounds__(256) void k_cvt(
    const float* __restrict__ w1, const float* __restrict__ w2,
    const float* __restrict__ wq, const float* __restrict__ wc,
    unsigned short* __restrict__ o, float* __restrict__ poolctx) {
  if (blockIdx.x == 0) {
    float4 z = {0.f, 0.f, 0.f, 0.f};
    ((float4*)poolctx)[threadIdx.x] = z;
    ((float4*)poolctx)[threadIdx.x + 256] = z;
  }
  int base = (blockIdx.x * 256 + threadIdx.x) * 4;
#pragma unroll
  for (int u = 0; u < 4; ++u) {
    int idx = base + u;
    float v;
    if (idx < 131072) v = w1[idx];
    else if (idx < 196608) v = w2[idx - 131072];
    else if (idx < 393216) v = wq[idx - 196608];
    else {
      int i = idx - 393216, n = i >> 8, k = i & 255;
      v = (n < 256) ? wc[n * 512 + k] : wc[(n - 256) * 512 + 256 + k];
    }
    o[idx] = (unsigned short)f2b(v);
  }
}

// ---------------------------------------------------------------------------
// K1: enc1 (K=512, depth-4 prefetched) + LN + relu -> enc2 (K=256) -> mf bf16
// ---------------------------------------------------------------------------
__global__ __launch_bounds__(256) void k_enc(
    const float* __restrict__ me,
    const unsigned short* __restrict__ wb1, const float* __restrict__ b1,
    const float* __restrict__ g, const float* __restrict__ lb,
    const unsigned short* __restrict__ wb2, const float* __restrict__ b2,
    unsigned short* __restrict__ mfb) {
  __shared__ float hh[16 * 260];
  __shared__ unsigned short rA[16 * 264];
  __shared__ unsigned short mfs[16 * 256];
  int tid = threadIdx.x, lane = tid & 63, w = tid >> 6;
  int row0 = blockIdx.x * 16;
  int m = lane & 15, q = lane >> 4;

  // ---- stage A: enc1, K=512, 16 k-steps, depth-4 prefetch on A and B
  {
    f32x4 acc[4];
#pragma unroll
    for (int i = 0; i < 4; ++i) acc[i] = (f32x4){0.f, 0.f, 0.f, 0.f};
    const float* ap = me + (size_t)(row0 + m) * 512 + q * 8;
    float4 pa0[4], pa1[4];
    bf16x8 pb[4][4];
#pragma unroll
    for (int d = 0; d < 4; ++d) {
      pa0[d] = *(const float4*)(ap + d * 32);
      pa1[d] = *(const float4*)(ap + d * 32 + 4);
#pragma unroll
      for (int nt = 0; nt < 4; ++nt)
        pb[d][nt] = *(const bf16x8*)(wb1 + (size_t)(w * 64 + nt * 16 + m) * 512 + d * 32 + q * 8);
    }
#pragma unroll
    for (int it = 0; it < 16; ++it) {
      int slot = it & 3;
      float4 a01 = pa0[slot], a23 = pa1[slot];
      bf16x8 bl0 = pb[slot][0], bl1 = pb[slot][1];
      bf16x8 bl2 = pb[slot][2], bl3 = pb[slot][3];
      if (it + 4 < 16) {
        pa0[slot] = *(const float4*)(ap + (it + 4) * 32);
        pa1[slot] = *(const float4*)(ap + (it + 4) * 32 + 4);
#pragma unroll
        for (int nt = 0; nt < 4; ++nt)
          pb[slot][nt] = *(const bf16x8*)(wb1 + (size_t)(w * 64 + nt * 16 + m) * 512 + (it + 4) * 32 + q * 8);
      }
      bf16x8 af;
      af[0] = f2b(a01.x); af[1] = f2b(a01.y); af[2] = f2b(a01.z); af[3] = f2b(a01.w);
      af[4] = f2b(a23.x); af[5] = f2b(a23.y); af[6] = f2b(a23.z); af[7] = f2b(a23.w);
      acc[0] = __builtin_amdgcn_mfma_f32_16x16x32_bf16(af, bl0, acc[0], 0, 0, 0);
      acc[1] = __builtin_amdgcn_mfma_f32_16x16x32_bf16(af, bl1, acc[1], 0, 0, 0);
      acc[2] = __builtin_amdgcn_mfma_f32_16x16x32_bf16(af, bl2, acc[2], 0, 0, 0);
      acc[3] = __builtin_amdgcn_mfma_f32_16x16x32_bf16(af, bl3, acc[3], 0, 0, 0);
    }
#pragma unroll
    for (int nt = 0; nt < 4; ++nt) {
      int col = w * 64 + nt * 16 + m;
      float bias = b1[col];
#pragma unroll
      for (int reg = 0; reg < 4; ++reg)
        hh[(q * 4 + reg) * 260 + col] = acc[nt][reg] + bias;
    }
  }
  __syncthreads();
  // ---- LN + relu -> rA (bf16)
  {
    float4 g4 = *(const float4*)(g + lane * 4);
    float4 lb4 = *(const float4*)(lb + lane * 4);
#pragma unroll
    for (int rr = 0; rr < 4; ++rr) {
      int r = w * 4 + rr;
      float4 v = *(const float4*)&hh[r * 260 + lane * 4];
      float s1 = v.x + v.y + v.z + v.w;
      float s2 = v.x * v.x + v.y * v.y + v.z * v.z + v.w * v.w;
#pragma unroll
      for (int o = 32; o > 0; o >>= 1) {
        s1 += __shfl_xor(s1, o, 64);
        s2 += __shfl_xor(s2, o, 64);
      }
      float mu = s1 * (1.f / 256.f);
      float var = s2 * (1.f / 256.f) - mu * mu;
      float rs = rsqrtf(var + 1e-5f);
      unsigned short y0 = (unsigned short)f2b(fmaxf((v.x - mu) * rs * g4.x + lb4.x, 0.f));
      unsigned short y1 = (unsigned short)f2b(fmaxf((v.y - mu) * rs * g4.y + lb4.y, 0.f));
      unsigned short y2 = (unsigned short)f2b(fmaxf((v.z - mu) * rs * g4.z + lb4.z, 0.f));
      unsigned short y3 = (unsigned short)f2b(fmaxf((v.w - mu) * rs * g4.w + lb4.w, 0.f));
      uint2 pk;
      pk.x = (unsigned)y0 | ((unsigned)y1 << 16);
      pk.y = (unsigned)y2 | ((unsigned)y3 << 16);
      *(uint2*)&rA[r * 264 + lane * 4] = pk;
    }
  }
  __syncthreads();
  // ---- stage B: enc2 (K=256) from rA; B depth-4 prefetch -> mfs bf16
  {
    f32x4 acc[4];
#pragma unroll
    for (int i = 0; i < 4; ++i) acc[i] = (f32x4){0.f, 0.f, 0.f, 0.f};
    bf16x8 pb[4][4];
#pragma unroll
    for (int d = 0; d < 4; ++d)
#pragma unroll
      for (int nt = 0; nt < 4; ++nt)
        pb[d][nt] = *(const bf16x8*)(wb2 + (size_t)(w * 64 + nt * 16 + m) * 256 + d * 32 + q * 8);
#pragma unroll
    for (int it = 0; it < 8; ++it) {
      int slot = it & 3;
      bf16x8 bl0 = pb[slot][0], bl1 = pb[slot][1];
      bf16x8 bl2 = pb[slot][2], bl3 = pb[slot][3];
      if (it + 4 < 8) {
#pragma unroll
        for (int nt = 0; nt < 4; ++nt)
          pb[slot][nt] = *(const bf16x8*)(wb2 + (size_t)(w * 64 + nt * 16 + m) * 256 + (it + 4) * 32 + q * 8);
      }
      bf16x8 af = *(const bf16x8*)&rA[m * 264 + it * 32 + q * 8];
      acc[0] = __builtin_amdgcn_mfma_f32_16x16x32_bf16(af, bl0, acc[0], 0, 0, 0);
      acc[1] = __builtin_amdgcn_mfma_f32_16x16x32_bf16(af, bl1, acc[1], 0, 0, 0);
      acc[2] = __builtin_amdgcn_mfma_f32_16x16x32_bf16(af, bl2, acc[2], 0, 0, 0);
      acc[3] = __builtin_amdgcn_mfma_f32_16x16x32_bf16(af, bl3, acc[3], 0, 0, 0);
    }
#pragma unroll
    for (int nt = 0; nt < 4; ++nt) {
      int col = w * 64 + nt * 16 + m;
      float bias = b2[col];
#pragma unroll
      for (int reg = 0; reg < 4; ++reg)
        mfs[(q * 4 + reg) * 256 + col] = (unsigned short)f2b(acc[nt][reg] + bias);
    }
  }
  __syncthreads();
  // coalesced bf16 copy-out: 16 rows x 256 ushort = 512 uint4
  {
    const uint4* src = (const uint4*)mfs;
    uint4* dst = (uint4*)(mfb + (size_t)row0 * 256);
    dst[tid] = src[tid];
    dst[tid + 256] = src[tid + 256];
  }
}

// ---------------------------------------------------------------------------
// K2: five 2048x256x256 GEMMs (q,k,v,a,b) — grid (128 rowblocks, 5 parts).
// ---------------------------------------------------------------------------
__global__ __launch_bounds__(256) void k_proj5(
    const unsigned short* __restrict__ mfb,
    const unsigned short* __restrict__ wqk,
    const unsigned short* __restrict__ wab,
    const float* __restrict__ bq, const float* __restrict__ cb1,
    float* __restrict__ qkv, float* __restrict__ amat,
    float* __restrict__ bmat) {
  int tid = threadIdx.x, lane = tid & 63, w = tid >> 6;
  int row0 = blockIdx.x * 16;
  int part = blockIdx.y;
  int m = lane & 15, q = lane >> 4;
  const unsigned short* W = (part < 3) ? (wqk + (size_t)part * 65536)
                                       : (wab + (size_t)(part - 3) * 65536);
  bf16x8 a[8];
#pragma unroll
  for (int ks = 0; ks < 8; ++ks)
    a[ks] = *(const bf16x8*)(mfb + (size_t)(row0 + m) * 256 + ks * 32 + q * 8);
  f32x4 acc[4];
#pragma unroll
  for (int i = 0; i < 4; ++i) acc[i] = (f32x4){0.f, 0.f, 0.f, 0.f};
  bf16x8 pb[4][4];
#pragma unroll
  for (int d = 0; d < 4; ++d)
#pragma unroll
    for (int nt = 0; nt < 4; ++nt)
      pb[d][nt] = *(const bf16x8*)(W + (size_t)(w * 64 + nt * 16 + m) * 256 + d * 32 + q * 8);
#pragma unroll
  for (int it = 0; it < 8; ++it) {
    int slot = it & 3;
    bf16x8 bl0 = pb[slot][0], bl1 = pb[slot][1];
    bf16x8 bl2 = pb[slot][2], bl3 = pb[slot][3];
    if (it + 4 < 8) {
#pragma unroll
      for (int nt = 0; nt < 4; ++nt)
        pb[slot][nt] = *(const bf16x8*)(W + (size_t)(w * 64 + nt * 16 + m) * 256 + (it + 4) * 32 + q * 8);
    }
    acc[0] = __builtin_amdgcn_mfma_f32_16x16x32_bf16(a[it], bl0, acc[0], 0, 0, 0);
    acc[1] = __builtin_amdgcn_mfma_f32_16x16x32_bf16(a[it], bl1, acc[1], 0, 0, 0);
    acc[2] = __builtin_amdgcn_mfma_f32_16x16x32_bf16(a[it], bl2, acc[2], 0, 0, 0);
    acc[3] = __builtin_amdgcn_mfma_f32_16x16x32_bf16(a[it], bl3, acc[3], 0, 0, 0);
  }
#pragma unroll
  for (int nt = 0; nt < 4; ++nt) {
    int col = w * 64 + nt * 16 + m;
    float bias;
    float* dst;
    int ld;
    if (part < 3) { bias = bq[part * 256 + col]; dst = qkv + part * 256; ld = 768; }
    else if (part == 3) { bias = cb1[col]; dst = amat; ld = 256; }
    else { bias = 0.f; dst = bmat; ld = 256; }
#pragma unroll
    for (int reg = 0; reg < 4; ++reg) {
      int row = row0 + q * 4 + reg;
      dst[(size_t)row * ld + col] = acc[nt][reg] + bias;
    }
  }
}

// ---------------------------------------------------------------------------
// ATTN fused: QK^T (fp32 VALU) + softmax + PV (bf16 MFMA) + pooled-ctx
// column-sum atomics. attn written bf16. grid = (b,h,sg) = 512 blocks.
// ---------------------------------------------------------------------------
__global__ __launch_bounds__(256) void k_attn_fused(
    const float* __restrict__ qkv, unsigned short* __restrict__ attnb,
    float* __restrict__ poolctx) {
  __shared__ float qs[32 * 32];
  __shared__ unsigned short ps[32 * 264];
  __shared__ unsigned short vt[32 * 264];
  int blk = blockIdx.x;
  int sg = blk & 7, bh = blk >> 3, h = bh & 7, b = bh >> 3;
  int tid = threadIdx.x, lane = tid & 63, w = tid >> 6;
  {
    int r = tid >> 3, c4 = tid & 7;
    float4 v = *(const float4*)(qkv + ((size_t)(b * 256 + sg * 32 + r)) * 768 + h * 32 + c4 * 4);
    *(float4*)&qs[r * 32 + c4 * 4] = v;
  }
  {
    const float4* vr = (const float4*)(qkv + ((size_t)(b * 256 + tid)) * 768 + 512 + h * 32);
#pragma unroll
    for (int d4 = 0; d4 < 8; ++d4) {
      float4 vv = vr[d4];
      vt[(d4 * 4 + 0) * 264 + tid] = (unsigned short)f2b(vv.x);
      vt[(d4 * 4 + 1) * 264 + tid] = (unsigned short)f2b(vv.y);
      vt[(d4 * 4 + 2) * 264 + tid] = (unsigned short)f2b(vv.z);
      vt[(d4 * 4 + 3) * 264 + tid] = (unsigned short)f2b(vv.w);
    }
  }
  __syncthreads();
  int r0 = w * 8;
  float sc[8][4];
#pragma unroll
  for (int r = 0; r < 8; ++r)
#pragma unroll
    for (int tt = 0; tt < 4; ++tt) sc[r][tt] = 0.f;
#pragma unroll
  for (int tt = 0; tt < 4; ++tt) {
    int t = tt * 64 + lane;
    const float4* kp = (const float4*)(qkv + ((size_t)(b * 256 + t)) * 768 + 256 + h * 32);
#pragma unroll
    for (int d4 = 0; d4 < 8; ++d4) {
      float4 kv = kp[d4];
#pragma unroll
      for (int r = 0; r < 8; ++r) {
        float4 qv = *(const float4*)&qs[(r0 + r) * 32 + d4 * 4];
        sc[r][tt] += qv.x * kv.x + qv.y * kv.y + qv.z * kv.z + qv.w * kv.w;
      }
    }
  }
  const float scale = 0.17677669529663689f;
  for (int r = 0; r < 8; ++r) {
    float v0 = sc[r][0] * scale, v1 = sc[r][1] * scale;
    float v2 = sc[r][2] * scale, v3 = sc[r][3] * scale;
    float mx = fmaxf(fmaxf(v0, v1), fmaxf(v2, v3));
#pragma unroll
    for (int o = 32; o > 0; o >>= 1) mx = fmaxf(mx, __shfl_xor(mx, o, 64));
    float e0 = expf(v0 - mx), e1 = expf(v1 - mx), e2 = expf(v2 - mx), e3 = expf(v3 - mx);
    float s = e0 + e1 + e2 + e3;
#pragma unroll
    for (int o = 32; o > 0; o >>= 1) s += __shfl_xor(s, o, 64);
    float inv = 1.f / s;
    unsigned short* prow = ps + (r0 + r) * 264;
    prow[lane] = (unsigned short)f2b(e0 * inv);
    prow[64 + lane] = (unsigned short)f2b(e1 * inv);
    prow[128 + lane] = (unsigned short)f2b(e2 * inv);
    prow[192 + lane] = (unsigned short)f2b(e3 * inv);
  }
  __syncthreads();
  // copy P (bf16) to global attnb, coalesced: 32 rows x 256 ushort.
  // 8 threads/row, each 32 ushorts = 4 uint4 at base seg*32.
  {
    int r = tid >> 3, seg = tid & 7;
    const uint4* src = (const uint4*)&ps[r * 264 + seg * 32];
    uint4* dst = (uint4*)(attnb + ((size_t)(bh * 256 + sg * 32 + r)) * 256 + seg * 32);
    dst[0] = src[0]; dst[1] = src[1]; dst[2] = src[2]; dst[3] = src[3];
  }
  // PV via MFMA + pooled column-sum atomics
  {
    int mt = w & 1, dt = w >> 1;
    int mm = lane & 15, qq = lane >> 4;
    f32x4 a = (f32x4){0.f, 0.f, 0.f, 0.f};
#pragma unroll
    for (int ks = 0; ks < 256; ks += 32) {
      bf16x8 af = *(const bf16x8*)&ps[(mt * 16 + mm) * 264 + ks + qq * 8];
      bf16x8 bf = *(const bf16x8*)&vt[(dt * 16 + mm) * 264 + ks + qq * 8];
      a = __builtin_amdgcn_mfma_f32_16x16x32_bf16(af, bf, a, 0, 0, 0);
    }
    float colsum = a[0] + a[1] + a[2] + a[3];
    colsum += __shfl_xor(colsum, 16, 64);
    colsum += __shfl_xor(colsum, 32, 64);
    if (lane < 16)
      atomicAdd(&poolctx[b * 256 + h * 32 + dt * 16 + mm], colsum);
  }
}

// ---------------------------------------------------------------------------
// attn_weights = mean over heads, bf16 in -> fp32 out
// ---------------------------------------------------------------------------
__global__ __launch_bounds__(256) void k_attn_mean(
    const unsigned short* __restrict__ attnb, float* __restrict__ out_aw) {
  int gid = blockIdx.x * 256 + threadIdx.x;  // 65536 over B*S*S/8
  int b = gid >> 13, e8 = gid & 8191;
  size_t e = (size_t)e8 * 8;
  float s0 = 0, s1 = 0, s2 = 0, s3 = 0, s4 = 0, s5 = 0, s6 = 0, s7 = 0;
#pragma unroll
  for (int h = 0; h < 8; ++h) {
    uint4 v = *(const uint4*)(attnb + (((size_t)(b * 8 + h)) << 16) + e);
    s0 += __uint_as_float(v.x << 16); s1 += __uint_as_float(v.x & 0xffff0000u);
    s2 += __uint_as_float(v.y << 16); s3 += __uint_as_float(v.y & 0xffff0000u);
    s4 += __uint_as_float(v.z << 16); s5 += __uint_as_float(v.z & 0xffff0000u);
    s6 += __uint_as_float(v.w << 16); s7 += __uint_as_float(v.w & 0xffff0000u);
  }
  float* dst = out_aw + ((size_t)b << 16) + e;
  float4 r0 = {s0 * 0.125f, s1 * 0.125f, s2 * 0.125f, s3 * 0.125f};
  float4 r1 = {s4 * 0.125f, s5 * 0.125f, s6 * 0.125f, s7 * 0.125f};
  *(float4*)dst = r0;
  *(float4*)(dst + 4) = r1;
}

// ---------------------------------------------------------------------------
// heads: pooled = poolctx/256 -> out-proj -> cons/hall, one block per b
// ---------------------------------------------------------------------------
__global__ __launch_bounds__(256) void k_heads(
    const float* __restrict__ poolctx,
    const float* __restrict__ outw, const float* __restrict__ outb,
    const float* __restrict__ cw1, const float* __restrict__ cb1,
    const float* __restrict__ cw2, const float* __restrict__ cb2,
    const float* __restrict__ hw1, const float* __restrict__ hb1,
    const float* __restrict__ hw2, const float* __restrict__ hb2,
    float* __restrict__ out) {
  int b = blockIdx.x, j = threadIdx.x;
  __shared__ float pc[256];
  __shared__ float psh[256];
  __shared__ float red[4];
  pc[j] = poolctx[b * 256 + j] * (1.f / 256.f);
  __syncthreads();
  float s = outb[j];
  const float4* wr = (const float4*)(outw + (size_t)j * 256);
  for (int k4 = 0; k4 < 64; ++k4) {
    float4 wv = wr[k4];
    const float* p = pc + k4 * 4;
    s += p[0] * wv.x + p[1] * wv.y + p[2] * wv.z + p[3] * wv.w;
  }
  psh[j] = s;
  __syncthreads();
  int jj = j & 127;
  bool isH = j >= 128;
  const float* w1 = isH ? hw1 : cw1;
  const float* bb1 = isH ? hb1 : cb1;
  const float* w2 = isH ? hw2 : cw2;
  float a = bb1[jj];
  const float4* w1r = (const float4*)(w1 + (size_t)jj * 256);
  for (int k4 = 0; k4 < 64; ++k4) {
    float4 wv = w1r[k4];
    const float* p = psh + k4 * 4;
    a += p[0] * wv.x + p[1] * wv.y + p[2] * wv.z + p[3] * wv.w;
  }
  float v = fmaxf(a, 0.f) * w2[jj];
#pragma unroll
  for (int o = 32; o > 0; o >>= 1) v += __shfl_xor(v, o, 64);
  if ((j & 63) == 0) red[j >> 6] = v;
  __syncthreads();
  if (j == 0) {
    float c = red[0] + red[1] + cb2[0];
    float h = red[2] + red[3] + hb2[0];
    out[b] = 1.f / (1.f + expf(-c));
    out[8 + b] = 1.f / (1.f + expf(-h));
  }
}

// ---------------------------------------------------------------------------
// pair scores, LDS-tiled 32x32 upper-triangular tiles (amat includes con_b1)
// ---------------------------------------------------------------------------
__global__ __launch_bounds__(256) void k_pairs(
    const float* __restrict__ amat, const float* __restrict__ bmat,
    const float* __restrict__ cw2, const float* __restrict__ cb2,
    float* __restrict__ M) {
  __shared__ float As[32 * 130];
  __shared__ float Bs[32 * 130];
  __shared__ float w2s[256];
  int blk = blockIdx.x;
  int b = blk / 36, tix = blk % 36;
  int it = 0, rem = tix;
  while (rem >= 8 - it) { rem -= 8 - it; ++it; }
  int jt = it + rem;
  int tid = threadIdx.x;
  int tj = tid & 15, ti = tid >> 4;
  w2s[tid] = cw2[tid];
  float acc00 = 0, acc01 = 0, acc10 = 0, acc11 = 0;
  const float* Ab = amat + ((size_t)(b * 256 + it * 32)) * 256;
  const float* Bb = bmat + ((size_t)(b * 256 + jt * 32)) * 256;
  for (int ch = 0; ch < 2; ++ch) {
    __syncthreads();
#pragma unroll
    for (int k = 0; k < 4; ++k) {
      int f = tid + k * 256;
      int r = f >> 5, c4 = f & 31;
      float4 va = *(const float4*)(Ab + (size_t)r * 256 + ch * 128 + c4 * 4);
      float4 vb = *(const float4*)(Bb + (size_t)r * 256 + ch * 128 + c4 * 4);
      int la = r * 130 + c4 * 4;
      *(float2*)&As[la] = make_float2(va.x, va.y);
      *(float2*)&As[la + 2] = make_float2(va.z, va.w);
      *(float2*)&Bs[la] = make_float2(vb.x, vb.y);
      *(float2*)&Bs[la + 2] = make_float2(vb.z, vb.w);
    }
    __syncthreads();
    const float* a0 = As + (2 * ti) * 130;
    const float* a1 = a0 + 130;
    const float* b0 = Bs + (2 * tj) * 130;
    const float* b1 = b0 + 130;
    const float* w2c = w2s + ch * 128;
    for (int d = 0; d < 128; d += 4) {
#pragma unroll
      for (int k = 0; k < 4; ++k) {
        float w = w2c[d + k];
        float av0 = a0[d + k], av1 = a1[d + k];
        float bv0 = b0[d + k], bv1 = b1[d + k];
        acc00 += fmaxf(av0 + bv0, 0.f) * w;
        acc01 += fmaxf(av0 + bv1, 0.f) * w;
        acc10 += fmaxf(av1 + bv0, 0.f) * w;
        acc11 += fmaxf(av1 + bv1, 0.f) * w;
      }
    }
  }
  float c2 = cb2[0];
  float s00 = 1.f / (1.f + expf(-(acc00 + c2)));
  float s01 = 1.f / (1.f + expf(-(acc01 + c2)));
  float s10 = 1.f / (1.f + expf(-(acc10 + c2)));
  float s11 = 1.f / (1.f + expf(-(acc11 + c2)));
  float* Mb = M + ((size_t)b << 16);
  int i0 = it * 32 + 2 * ti, i1 = i0 + 1;
  int j0 = jt * 32 + 2 * tj, j1 = j0 + 1;
  if (it != jt) {
    Mb[i0 * 256 + j0] = s00; Mb[j0 * 256 + i0] = s00;
    Mb[i0 * 256 + j1] = s01; Mb[j1 * 256 + i0] = s01;
    Mb[i1 * 256 + j0] = s10; Mb[j0 * 256 + i1] = s10;
    Mb[i1 * 256 + j1] = s11; Mb[j1 * 256 + i1] = s11;
  } else {
    if (j0 > i0) { Mb[i0 * 256 + j0] = s00; Mb[j0 * 256 + i0] = s00; }
    else if (j0 == i0) Mb[i0 * 256 + j0] = 0.f;
    if (j1 > i0) { Mb[i0 * 256 + j1] = s01; Mb[j1 * 256 + i0] = s01; }
    if (j0 > i1) { Mb[i1 * 256 + j0] = s10; Mb[j0 * 256 + i1] = s10; }
    if (j1 > i1) { Mb[i1 * 256 + j1] = s11; Mb[j1 * 256 + i1] = s11; }
    else if (j1 == i1) Mb[i1 * 256 + j1] = 0.f;
  }
}

// ---------------------------------------------------------------------------
extern "C" void kernel_launch(void* const* d_in, const int* in_sizes, int n_in,
                              void* d_out, int out_size, void* d_ws, size_t ws_size,
                              hipStream_t stream) {
  const float* me        = (const float*)d_in[0];
  const float* enc_w1    = (const float*)d_in[1];
  const float* enc_b1    = (const float*)d_in[2];
  const float* ln_g      = (const float*)d_in[3];
  const float* ln_b      = (const float*)d_in[4];
  const float* enc_w2    = (const float*)d_in[5];
  const float* enc_b2    = (const float*)d_in[6];
  const float* in_proj_w = (const float*)d_in[7];
  const float* in_proj_b = (const float*)d_in[8];
  const float* out_w     = (const float*)d_in[9];
  const float* out_b     = (const float*)d_in[10];
  const float* cons_w1   = (const float*)d_in[11];
  const float* cons_b1   = (const float*)d_in[12];
  const float* cons_w2   = (const float*)d_in[13];
  const float* cons_b2   = (const float*)d_in[14];
  const float* hall_w1   = (const float*)d_in[15];
  const float* hall_b1   = (const float*)d_in[16];
  const float* hall_w2   = (const float*)d_in[17];
  const float* hall_b2   = (const float*)d_in[18];
  const float* con_w1    = (const float*)d_in[19];
  const float* con_b1    = (const float*)d_in[20];
  const float* con_w2    = (const float*)d_in[21];
  const float* con_b2    = (const float*)d_in[22];

  // workspace layout (float offsets) — attnb is 4,194,304 ushorts =
  // 2,097,152 floats (B*NH*S*S). [R5/R6 bug: amat/bmat were placed inside
  // attnb's extent and got clobbered by the attn copy-out.]
  float* ws = (float*)d_ws;
  float* qkv  = ws;                                        // [0, 1572864)
  unsigned short* attnb = (unsigned short*)(ws + 1572864); // [1572864, 3670016)
  float* amat = ws + 3670016;                              // [3670016, 4194304)
  float* bmat = ws + 4194304;                              // [4194304, 4718592)
  unsigned short* mfb = (unsigned short*)(ws + 4718592);   // [4718592, 4980736)
  unsigned short* wbf = (unsigned short*)(ws + 4980736);   // [4980736, 5242880)
  float* poolctx = ws + 5242880;                           // [5242880, 5244928)

  unsigned short* wb1 = wbf;            // enc_w1  [256][512]
  unsigned short* wb2 = wbf + 131072;   // enc_w2  [256][256]
  unsigned short* wqk = wbf + 196608;   // in_proj [768][256]
  unsigned short* wab = wbf + 393216;   // con_w1 repacked [512][256]

  float* out    = (float*)d_out;
  float* out_M  = out + 16;
  float* out_aw = out + 16 + 524288;

  k_cvt<<<512, 256, 0, stream>>>(enc_w1, enc_w2, in_proj_w, con_w1, wbf, poolctx);
  k_enc<<<128, 256, 0, stream>>>(me, wb1, enc_b1, ln_g, ln_b, wb2, enc_b2, mfb);
  k_proj5<<<dim3(128, 5), 256, 0, stream>>>(mfb, wqk, wab, in_proj_b, con_b1,
                                            qkv, amat, bmat);
  k_attn_fused<<<512, 256, 0, stream>>>(qkv, attnb, poolctx);
  k_attn_mean<<<256, 256, 0, stream>>>(attnb, out_aw);
  k_heads<<<8, 256, 0, stream>>>(poolctx, out_w, out_b,
                                 cons_w1, cons_b1, cons_w2, cons_b2,
                                 hall_w1, hall_b1, hall_w2, hall_b2, out);
  k_pairs<<<288, 256, 0, stream>>>(amat, bmat, con_w2, con_b2, out_M);
}